// Round 13
// baseline (231.318 us; speedup 1.0000x reference)
//
#include <hip/hip_runtime.h>

typedef unsigned short ushort_t;
typedef __attribute__((ext_vector_type(8))) short bh8;     // 8 bf16 (4 VGPRs)
typedef __attribute__((ext_vector_type(4))) float f4;      // 4 fp32 acc
typedef __attribute__((ext_vector_type(4))) unsigned int u4;

__device__ __forceinline__ ushort_t f2bf(float f) {
  unsigned u = __float_as_uint(f);
  return (ushort_t)((u + 0x7FFFu + ((u >> 16) & 1u)) >> 16);
}
__device__ __forceinline__ float bf2f(ushort_t v) {
  return __uint_as_float(((unsigned)v) << 16);
}

// ---------------------------------------------------------------------------
// bf16 MFMA GEMM core, abt form, LDS passed in (20480 B: As 10240 + Bs 10240)
// ---------------------------------------------------------------------------
template <typename OutT>
__device__ __forceinline__ void gemm_abt_core(
    char* smem,
    const ushort_t* __restrict__ A, const ushort_t* __restrict__ B,
    OutT* __restrict__ C, int ldA, int ldB, int ldC, int K, int m0, int n0)
{
  ushort_t* As = (ushort_t*)smem;
  ushort_t* Bs = (ushort_t*)(smem + 10240);
  int t = threadIdx.x;
  int lane = t & 63, w = t >> 6;
  int quad = lane >> 4, l15 = lane & 15;
  int wm = w >> 1, wn = w & 1;
  f4 acc[4][4];
  #pragma unroll
  for (int mi = 0; mi < 4; ++mi)
    #pragma unroll
    for (int ni = 0; ni < 4; ++ni) acc[mi][ni] = (f4)0.f;
  int row = t >> 1, kh = (t & 1) * 16;
  for (int k0 = 0; k0 < K; k0 += 32) {
    if (k0) __syncthreads();
    {
      const u4* ga = (const u4*)(A + (m0 + row) * ldA + k0 + kh);
      u4 v0 = ga[0], v1 = ga[1];
      u4* da = (u4*)(As + row * 40 + kh); da[0] = v0; da[1] = v1;
      const u4* gb = (const u4*)(B + (n0 + row) * ldB + k0 + kh);
      u4 u0 = gb[0], u1 = gb[1];
      u4* db = (u4*)(Bs + row * 40 + kh); db[0] = u0; db[1] = u1;
    }
    __syncthreads();
    bh8 af[4], bfv[4];
    #pragma unroll
    for (int mi = 0; mi < 4; ++mi)
      af[mi] = *(bh8*)(As + (wm * 64 + mi * 16 + l15) * 40 + quad * 8);
    #pragma unroll
    for (int ni = 0; ni < 4; ++ni)
      bfv[ni] = *(bh8*)(Bs + (wn * 64 + ni * 16 + l15) * 40 + quad * 8);
    #pragma unroll
    for (int mi = 0; mi < 4; ++mi)
      #pragma unroll
      for (int ni = 0; ni < 4; ++ni)
        acc[mi][ni] = __builtin_amdgcn_mfma_f32_16x16x32_bf16(af[mi], bfv[ni], acc[mi][ni], 0, 0, 0);
  }
  #pragma unroll
  for (int mi = 0; mi < 4; ++mi)
    #pragma unroll
    for (int ni = 0; ni < 4; ++ni)
      #pragma unroll
      for (int r = 0; r < 4; ++r) {
        int mg = m0 + wm * 64 + mi * 16 + quad * 4 + r;
        int ng = n0 + wn * 64 + ni * 16 + l15;
        if constexpr (sizeof(OutT) == 4) C[mg * ldC + ng] = acc[mi][ni][r];
        else C[mg * ldC + ng] = (OutT)f2bf(acc[mi][ni][r]);
      }
}

// ---------------------------------------------------------------------------
// STAGE 1 (all parts mutually independent):
//   blocks 0..2047    : bf16 cast into arena
//   blocks 2048..2559 : gather indices w/ INLINE offset projection (fp32)
//   blocks 2560..2687 : gemm4 in fp32 from ORIGINAL addk/Wattn -> tmp_bf
// Cast i-unit ranges: q 65536 | xin 850816 | addk 16384 | Wcat 262144 |
//   Wlvl 524288 -> total4 = 1719168.
// (round-12 bug: total4 left at 1850240 after dropping the Wattn4 range —
//  Wlvl branch overran by 524288 elems, clobbering tmp_bf in-kernel.)
// ---------------------------------------------------------------------------
__global__ __launch_bounds__(256) void k_stage1(
    const float* __restrict__ q, const float* __restrict__ xin,
    const float* __restrict__ addk, const float* __restrict__ Wval,
    const float* __restrict__ Wattn, ushort_t* __restrict__ arena,
    const float* __restrict__ Woff, const float* __restrict__ boff,
    const float* __restrict__ refpts, const int* __restrict__ shapes,
    const int* __restrict__ lvlst, int* __restrict__ fidx,
    ushort_t* __restrict__ tmp)
{
  __shared__ __align__(16) float smem[2 * 16 * 65];   // 8320 B
  int bx = blockIdx.x;
  if (bx < 2048) {
    const int total4 = 1719168;
    for (int i = bx * 256 + threadIdx.x; i < total4; i += 2048 * 256) {
      const float* src; ushort_t* dst; int e;
      if (i < 65536)        { src = q    + i * 4;            dst = arena + i * 4; }
      else if (i < 916352)  { e = i - 65536;  src = xin  + e * 4; dst = arena + 262144  + e * 4; }
      else if (i < 932736)  { e = i - 916352; src = addk + e * 4; dst = arena + 3665408 + e * 4; }
      else if (i < 1194880) {                     // Wcat: [Wv1 row | Wv2 row]
        e = i - 932736; int el = e * 4;           // el in [0, 1048576)
        int h = el >> 17, r = el & 131071;
        int c = r >> 9, k = r & 511;
        src = Wval + (2 * h + (k >> 8)) * 65536 + c * 256 + (k & 255);
        dst = arena + 3730944 + el;
      }
      else {                                      // Wattn level mats 0..31
        e = i - 1194880;                          // e in [0, 524288)
        src = Wattn + e * 4;
        dst = arena + 6352384 + e * 4;
      }
      float4 v = *(const float4*)src;
      ushort4 o; o.x = f2bf(v.x); o.y = f2bf(v.y); o.z = f2bf(v.z); o.w = f2bf(v.w);
      *(ushort4*)dst = o;
    }
  } else if (bx < 2560) {
    // ---- indices with inline offset projection: 2 queries per block ----
    int b2 = bx - 2048;
    int t = threadIdx.x;
    smem[t]       = q[b2 * 512 + t];
    smem[t + 256] = q[b2 * 512 + 256 + t];
    __syncthreads();
    int qh = t >> 7, tt = t & 127;                 // tt = h*16 + l*4 + p
    const float* qs = smem + qh * 256;
    const float* w0 = Woff + (2 * tt) * 256;
    const float* w1 = w0 + 256;
    float o0 = 0.f, o1 = 0.f;
    #pragma unroll 4
    for (int d = 0; d < 256; d += 4) {
      float4 a = *(const float4*)(qs + d);
      float4 x = *(const float4*)(w0 + d);
      float4 y = *(const float4*)(w1 + d);
      o0 += a.x * x.x + a.y * x.y + a.z * x.z + a.w * x.w;
      o1 += a.x * y.x + a.y * y.y + a.z * y.z + a.w * y.w;
    }
    int b = b2 * 2 + qh;
    int l = (tt >> 2) & 3;
    float off0 = o0 + boff[2 * tt];
    float off1 = o1 + boff[2 * tt + 1];
    int Hi = shapes[2 * l], Wi = shapes[2 * l + 1];
    float Hf = (float)Hi, Wf = (float)Wi;
    float r0 = refpts[b * 8 + 2 * l], r1 = refpts[b * 8 + 2 * l + 1];
    float l0 = fminf(fmaxf(r0 + off0 / Wf, 0.f), 0.999f);
    float l1 = fminf(fmaxf(r1 + off1 / Hf, 0.f), 0.999f);
    int i0 = (int)(l0 * Hf);
    int i1 = (int)(l1 * Wf);
    fidx[b * 128 + tt] = i0 + i1 * Hi + lvlst[l];
  } else {
    // ---- gemm4 fp32: tmp[h] = addk @ WattnAdd[h]^T (64-tile), bf16 out ----
    int e = bx - 2560;                             // 128 = 8 h x 16 tiles
    int h = e >> 4, tile = e & 15;
    int m0 = (tile >> 2) * 64, n0 = (tile & 3) * 64;
    const float* A = addk;
    const float* B = Wattn + h * 262144 + 262144;
    float (*As)[65] = (float(*)[65])smem;
    float (*Bs)[65] = (float(*)[65])(smem + 16 * 65);
    int t = threadIdx.x;
    int tm = t & 15, tn = t >> 4;
    int lr = t >> 4, lc = t & 15;
    float acc[4][4] = {};
    for (int k0 = 0; k0 < 256; k0 += 16) {
      if (k0) __syncthreads();
      #pragma unroll
      for (int i = 0; i < 4; ++i) {
        int r = lr + i * 16;
        As[lc][r] = A[(m0 + r) * 256 + k0 + lc];
        Bs[lc][r] = B[(n0 + r) * 256 + k0 + lc];
      }
      __syncthreads();
      #pragma unroll
      for (int k = 0; k < 16; ++k) {
        float a[4], b[4];
        #pragma unroll
        for (int i = 0; i < 4; ++i) a[i] = As[k][tm * 4 + i];
        #pragma unroll
        for (int j = 0; j < 4; ++j) b[j] = Bs[k][tn * 4 + j];
        #pragma unroll
        for (int i = 0; i < 4; ++i)
          #pragma unroll
          for (int j = 0; j < 4; ++j) acc[i][j] += a[i] * b[j];
      }
    }
    ushort_t* Cb = tmp + h * 65536;
    #pragma unroll
    for (int i = 0; i < 4; ++i)
      #pragma unroll
      for (int j = 0; j < 4; ++j)
        Cb[(m0 + tm * 4 + i) * 256 + n0 + tn * 4 + j] = f2bf(acc[i][j]);
  }
}

// ---------------------------------------------------------------------------
// MFMA level-attention body (round-10 structure; flattened block index)
// ---------------------------------------------------------------------------
__device__ __forceinline__ void attn_mfma_body(
    char* smemc,
    const ushort_t* __restrict__ qbf, const ushort_t* __restrict__ xbf,
    const ushort_t* __restrict__ Wlvl, const int* __restrict__ fidx,
    float* __restrict__ attnP, int bx)
{
  unsigned* Bs = (unsigned*)smemc;               // 64*34 words = 8704 B
  ushort_t* As = (ushort_t*)(smemc + 8704);      // 64*72 ushort = 9216 B
  int* fis = (int*)(smemc + 17920);              // 1024 B
  float* Nlds = (float*)smemc;                   // 64*68 f32 (overlay)

  int h = bx >> 8, l = (bx >> 6) & 3, g = bx & 63;
  int ch = g & 3, g2 = g >> 2;
  int p = g2 >> 2, tg = g2 & 3;
  int c0 = ch * 64;
  int t = threadIdx.x;
  int lane = t & 63, w = t >> 6;
  int quad = lane >> 4, l15 = lane & 15;
  int qcol = p * 4 + tg;
  fis[t] = fidx[(tg * 256 + t) * 128 + h * 16 + l * 4 + p];
  __syncthreads();
  f4 acc[4];
  #pragma unroll
  for (int mi = 0; mi < 4; ++mi) acc[mi] = (f4)0.f;

  int cl = t & 63, sg = t >> 6;
  for (int jt = 0; jt < 4; ++jt) {
    if (jt) __syncthreads();
    unsigned vv[16];
    #pragma unroll
    for (int rr = 0; rr < 16; ++rr)
      vv[rr] = xbf[fis[jt * 64 + sg * 16 + rr] * 256 + c0 + cl];
    #pragma unroll
    for (int i = 0; i < 4; ++i) {
      uint2 w2; w2.x = vv[i * 4] | (vv[i * 4 + 1] << 16);
      w2.y = vv[i * 4 + 2] | (vv[i * 4 + 3] << 16);
      *(uint2*)&Bs[cl * 34 + sg * 8 + i * 2] = w2;
    }
    {
      int u = t >> 2, jj0 = (t & 3) * 16;
      const u4* src = (const u4*)(qbf + (u * 16 + qcol) * 256 + jt * 64 + jj0);
      u4 s0 = src[0], s1 = src[1];
      u4* dst = (u4*)(As + u * 72 + jj0);
      dst[0] = s0; dst[1] = s1;
    }
    __syncthreads();
    #pragma unroll
    for (int ks = 0; ks < 2; ++ks) {
      bh8 af[4], bfv;
      #pragma unroll
      for (int mi = 0; mi < 4; ++mi)
        af[mi] = *(bh8*)(As + (mi * 16 + l15) * 72 + ks * 32 + quad * 8);
      {
        const unsigned* bp = &Bs[(w * 16 + l15) * 34 + ks * 16 + quad * 4];
        uint2 b0 = *(const uint2*)bp;
        uint2 b1 = *(const uint2*)(bp + 2);
        u4 bb; bb.x = b0.x; bb.y = b0.y; bb.z = b1.x; bb.w = b1.y;
        bfv = __builtin_bit_cast(bh8, bb);
      }
      #pragma unroll
      for (int mi = 0; mi < 4; ++mi)
        acc[mi] = __builtin_amdgcn_mfma_f32_16x16x32_bf16(af[mi], bfv, acc[mi], 0, 0, 0);
    }
  }
  __syncthreads();
  #pragma unroll
  for (int mi = 0; mi < 4; ++mi)
    *(f4*)&Nlds[(w * 16 + l15) * 68 + mi * 16 + quad * 4] = acc[mi];
  __syncthreads();
  {
    int a = t >> 6, u = t & 63;
    const ushort_t* Wr = Wlvl + (h * 4 + l) * 65536 + (a * 64 + u) * 256 + c0;
    float s = 0.f;
    #pragma unroll
    for (int cc = 0; cc < 8; ++cc) {
      u4 wv = *(const u4*)(Wr + cc * 8);
      int cb = cc * 8;
      s += __uint_as_float(wv.x << 16)         * Nlds[(cb + 0) * 68 + u];
      s += __uint_as_float(wv.x & 0xffff0000u) * Nlds[(cb + 1) * 68 + u];
      s += __uint_as_float(wv.y << 16)         * Nlds[(cb + 2) * 68 + u];
      s += __uint_as_float(wv.y & 0xffff0000u) * Nlds[(cb + 3) * 68 + u];
      s += __uint_as_float(wv.z << 16)         * Nlds[(cb + 4) * 68 + u];
      s += __uint_as_float(wv.z & 0xffff0000u) * Nlds[(cb + 5) * 68 + u];
      s += __uint_as_float(wv.w << 16)         * Nlds[(cb + 6) * 68 + u];
      s += __uint_as_float(wv.w & 0xffff0000u) * Nlds[(cb + 7) * 68 + u];
    }
    attnP[ch * 131072 + (h * 16 + l * 4 + a) * 1024 + u * 16 + qcol] = s;
  }
}

// ---------------------------------------------------------------------------
// STAGE 2: level attention (blocks 0..2047) + gemm5 (blocks 2048..2175)
// ---------------------------------------------------------------------------
__global__ __launch_bounds__(256) void k_fused_attn(
    const ushort_t* __restrict__ qbf, const ushort_t* __restrict__ xbf,
    const ushort_t* __restrict__ Wlvl, const int* __restrict__ fidx,
    float* __restrict__ attnP,
    const ushort_t* __restrict__ tmp, float* __restrict__ attn)
{
  __shared__ __align__(16) char smem[20480];
  int bx = blockIdx.x;
  if (bx < 2048) {
    attn_mfma_body(smem, qbf, xbf, Wlvl, fidx, attnP, bx);
  } else {
    int e = bx - 2048;                         // 128 blocks: (8,2,8) flattened
    int h = e >> 4, rem = e & 15, my = rem >> 3, nx = rem & 7;
    gemm_abt_core<float>(smem, tmp + h * 65536, qbf, attn + h * 278528 + 16384,
                         256, 256, 1024, 256, my * 128, nx * 128);
  }
}

// ---------------------------------------------------------------------------
// softmax: rows<16 = sum of the 4 attnP partial slices; rows>=16 from attn.
// ---------------------------------------------------------------------------
__global__ __launch_bounds__(256) void k_softmax(
    float* __restrict__ attn, const float* __restrict__ attnP,
    ushort_t* __restrict__ attn2bf, float* __restrict__ s1, float* __restrict__ s2)
{
  __shared__ float red[8][32];
  int h = blockIdx.y;
  int b = blockIdx.x * 32 + (threadIdx.x & 31);
  int rg = threadIdx.x >> 5;
  const int R0 = rg * 34;
  float* col = attn + h * 278528 + b;
  float v[34];
  float m = -1e30f;
  #pragma unroll
  for (int i = 0; i < 34; ++i) {
    int r = R0 + i;
    float x;
    if (r < 16) {
      int idx = (h * 16 + r) * 1024 + b;
      x = attnP[idx] + attnP[131072 + idx] + attnP[262144 + idx] + attnP[393216 + idx];
    } else {
      x = col[r * 1024];
    }
    v[i] = x;
    m = fmaxf(m, x);
  }
  red[rg][threadIdx.x & 31] = m;
  __syncthreads();
  #pragma unroll
  for (int j = 0; j < 8; ++j) m = fmaxf(m, red[j][threadIdx.x & 31]);
  float sum = 0.f;
  #pragma unroll
  for (int i = 0; i < 34; ++i) { v[i] = expf(v[i] - m); sum += v[i]; }
  __syncthreads();
  red[rg][threadIdx.x & 31] = sum;
  __syncthreads();
  float tot = 0.f;
  #pragma unroll
  for (int j = 0; j < 8; ++j) tot += red[j][threadIdx.x & 31];
  float inv = 1.f / tot;
  #pragma unroll
  for (int i = 0; i < 34; ++i) {
    int r = R0 + i;
    float x = v[i] * inv;
    if (r < 16) col[r * 1024] = x;
    else attn2bf[h * 262144 + (r - 16) * 1024 + b] = f2bf(x);
  }
  if (rg == 0) {
    float sa = 0.f;
    #pragma unroll
    for (int i = 0; i < 16; ++i) sa += v[i];
    float sn = sa * inv;
    s1[h * 1024 + b] = sn;
    s2[h * 1024 + b] = 1.f - sn;
  }
}

// ---------------------------------------------------------------------------
// STAGE 4: kbar (blocks 0..1023) + TN GEMM abar (blocks 1024..1151)
// ---------------------------------------------------------------------------
__global__ __launch_bounds__(256) void k_fused_kbar_tn(
    const ushort_t* __restrict__ xbf, const float* __restrict__ attn,
    const int* __restrict__ fidx, const ushort_t* __restrict__ attn2,
    const ushort_t* __restrict__ addk, ushort_t* __restrict__ kabar)
{
  __shared__ __align__(16) unsigned Asu[128 * 20];
  __shared__ __align__(16) unsigned Bsu[128 * 20];
  if (blockIdx.x < 1024) {
    int h = blockIdx.x >> 7, b0 = (blockIdx.x & 127) * 8;
    int t = threadIdx.x;
    int qi = t >> 5, oct = t & 31;
    int b = b0 + qi;
    float sacc[8] = {};
    #pragma unroll
    for (int r = 0; r < 16; ++r) {
      float aw = attn[(h * 272 + r) * 1024 + b];
      int row = fidx[b * 128 + h * 16 + r];
      u4 v = *(const u4*)(xbf + row * 256 + oct * 8);
      sacc[0] += aw * __uint_as_float(v.x << 16);
      sacc[1] += aw * __uint_as_float(v.x & 0xffff0000u);
      sacc[2] += aw * __uint_as_float(v.y << 16);
      sacc[3] += aw * __uint_as_float(v.y & 0xffff0000u);
      sacc[4] += aw * __uint_as_float(v.z << 16);
      sacc[5] += aw * __uint_as_float(v.z & 0xffff0000u);
      sacc[6] += aw * __uint_as_float(v.w << 16);
      sacc[7] += aw * __uint_as_float(v.w & 0xffff0000u);
    }
    u4 o;
    o.x = (unsigned)f2bf(sacc[0]) | ((unsigned)f2bf(sacc[1]) << 16);
    o.y = (unsigned)f2bf(sacc[2]) | ((unsigned)f2bf(sacc[3]) << 16);
    o.z = (unsigned)f2bf(sacc[4]) | ((unsigned)f2bf(sacc[5]) << 16);
    o.w = (unsigned)f2bf(sacc[6]) | ((unsigned)f2bf(sacc[7]) << 16);
    *(u4*)(kabar + (h * 1024 + b) * 512 + oct * 8) = o;
  } else {
    int e = blockIdx.x - 1024;                 // 128 blocks: (2,8,8) flattened
    int h = e >> 4, rem = e & 15, my = rem >> 1, nx = rem & 1;
    const ushort_t* A = attn2 + h * 262144;
    const ushort_t* B = addk;
    ushort_t* C = kabar + h * 524288;
    int m0 = my * 128, n0 = nx * 128;
    int t = threadIdx.x;
    int lane = t & 63, w = t >> 6;
    int quad = lane >> 4, l15 = lane & 15;
    int wm = w >> 1, wn = w & 1;
    f4 acc[4][4];
    #pragma unroll
    for (int mi = 0; mi < 4; ++mi)
      #pragma unroll
      for (int ni = 0; ni < 4; ++ni) acc[mi][ni] = (f4)0.f;
    int col = t & 127, half = t >> 7;
    for (int k0 = 0; k0 < 256; k0 += 32) {
      if (k0) __syncthreads();
      #pragma unroll
      for (int i = 0; i < 4; ++i) {
        int kpp = half * 4 + i;
        int kk = k0 + kpp * 4;
        unsigned x0 = A[(kk + 0) * 1024 + m0 + col];
        unsigned x1 = A[(kk + 1) * 1024 + m0 + col];
        unsigned x2 = A[(kk + 2) * 1024 + m0 + col];
        unsigned x3 = A[(kk + 3) * 1024 + m0 + col];
        uint2 va; va.x = x0 | (x1 << 16); va.y = x2 | (x3 << 16);
        *(uint2*)&Asu[col * 20 + kpp * 2] = va;
        unsigned y0 = B[(kk + 0) * 256 + n0 + col];
        unsigned y1 = B[(kk + 1) * 256 + n0 + col];
        unsigned y2 = B[(kk + 2) * 256 + n0 + col];
        unsigned y3 = B[(kk + 3) * 256 + n0 + col];
        uint2 vb; vb.x = y0 | (y1 << 16); vb.y = y2 | (y3 << 16);
        *(uint2*)&Bsu[col * 20 + kpp * 2] = vb;
      }
      __syncthreads();
      bh8 af[4], bfv[4];
      #pragma unroll
      for (int mi = 0; mi < 4; ++mi)
        af[mi] = *(bh8*)((const ushort_t*)Asu + (wm * 64 + mi * 16 + l15) * 40 + quad * 8);
      #pragma unroll
      for (int ni = 0; ni < 4; ++ni)
        bfv[ni] = *(bh8*)((const ushort_t*)Bsu + (wn * 64 + ni * 16 + l15) * 40 + quad * 8);
      #pragma unroll
      for (int mi = 0; mi < 4; ++mi)
        #pragma unroll
        for (int ni = 0; ni < 4; ++ni)
          acc[mi][ni] = __builtin_amdgcn_mfma_f32_16x16x32_bf16(af[mi], bfv[ni], acc[mi][ni], 0, 0, 0);
    }
    #pragma unroll
    for (int mi = 0; mi < 4; ++mi)
      #pragma unroll
      for (int ni = 0; ni < 4; ++ni)
        #pragma unroll
        for (int r = 0; r < 4; ++r) {
          int mg = m0 + wm * 64 + mi * 16 + quad * 4 + r;
          int ng = n0 + wn * 64 + ni * 16 + l15;
          C[mg * 512 + 256 + ng] = f2bf(acc[mi][ni][r]);
        }
  }
}

// Y[h] = kabar[h] (1024x512) @ Wcat[h]^T (256 rows x 512 k, stride 131072/head)
__global__ __launch_bounds__(256) void gemm_val_k(
    const ushort_t* __restrict__ kabar, const ushort_t* __restrict__ Wcat,
    float* __restrict__ Y)
{
  __shared__ __align__(16) char smem[20480];
  int h = blockIdx.z;
  gemm_abt_core<float>(smem, kabar + h * 524288, Wcat + h * 131072, Y + h * 262144,
                       512, 512, 256, 512, blockIdx.y * 128, blockIdx.x * 128);
}

// ------------------------------- final combine ------------------------------
__global__ __launch_bounds__(256) void k_combine(
    const float* __restrict__ q, const float* __restrict__ Wmix,
    const float* __restrict__ Y,
    const float* __restrict__ s1, const float* __restrict__ s2,
    const float* __restrict__ bval, float* __restrict__ out)
{
  int b = blockIdx.x, c = threadIdx.x;
  float w[9];
  float m = -1e30f;
  #pragma unroll
  for (int j = 0; j < 9; ++j) { w[j] = Wmix[c * 9 + j]; m = fmaxf(m, w[j]); }
  float tot = 0.f;
  #pragma unroll
  for (int j = 0; j < 9; ++j) { w[j] = expf(w[j] - m); tot += w[j]; }
  float inv = 1.f / tot;
  float res = q[b * 256 + c] * w[8] * inv;
  #pragma unroll
  for (int hh = 0; hh < 8; ++hh) {
    float y = Y[(hh * 1024 + b) * 256 + c]
            + s1[hh * 1024 + b] * bval[(2 * hh) * 256 + c]
            + s2[hh * 1024 + b] * bval[(2 * hh + 1) * 256 + c];
    res += w[hh] * inv * y;
  }
  out[b * 256 + c] = res;
}

extern "C" void kernel_launch(void* const* d_in, const int* in_sizes, int n_in,
                              void* d_out, int out_size, void* d_ws, size_t ws_size,
                              hipStream_t stream) {
  (void)in_sizes; (void)n_in; (void)out_size; (void)ws_size;
  const float* q      = (const float*)d_in[0];
  const float* refpts = (const float*)d_in[1];
  const float* xin    = (const float*)d_in[2];
  const int*   shapes = (const int*)d_in[3];
  const float* addk   = (const float*)d_in[4];
  const int*   lvlst  = (const int*)d_in[5];
  const float* Woff   = (const float*)d_in[6];
  const float* boff   = (const float*)d_in[7];
  const float* Wattn  = (const float*)d_in[8];
  const float* Wval   = (const float*)d_in[9];
  const float* bval   = (const float*)d_in[10];
  const float* Wmix   = (const float*)d_in[11];
  float* out = (float*)d_out;
  float* ws  = (float*)d_ws;

  int*   fidx    = (int*)ws;                  // [0, 131072)
  float* s1      = ws + 393216;               // 8192
  float* s2      = ws + 401408;               // 8192
  float* attn    = ws + 409600;               // 8*272*1024 fp32 (dead after stage4)
  float* Y       = ws + 409600;               // overlays attn (written by gemm_val_k)
  ushort_t* arena = (ushort_t*)(ws + 2637824);
  ushort_t* q_bf     = arena;                 // 262144
  ushort_t* xin_bf   = arena + 262144;        // 3403264
  ushort_t* addk_bf  = arena + 3665408;       // 65536
  ushort_t* Wcat_bf  = arena + 3730944;       // 1048576 (stride 131072/head)
  ushort_t* Wlvl_bf  = arena + 6352384;       // 2097152
  ushort_t* tmp_bf   = arena + 8449536;       // 524288
  ushort_t* attn2_bf = arena + 8973824;       // 2097152
  ushort_t* kabar_bf = arena + 11070976;      // 4194304 (8*1024*512)
  float* attnP = (float*)(arena + 15265280);  // 4 * 131072 f (per-ch partials)

  k_stage1<<<2688, 256, 0, stream>>>(q, xin, addk, Wval, Wattn, arena,
                                     Woff, boff, refpts, shapes, lvlst,
                                     fidx, tmp_bf);
  k_fused_attn<<<2176, 256, 0, stream>>>(q_bf, xin_bf, Wlvl_bf, fidx, attnP,
                                         tmp_bf, attn);
  k_softmax<<<dim3(32, 8), 256, 0, stream>>>(attn, attnP, attn2_bf, s1, s2);
  k_fused_kbar_tn<<<1152, 256, 0, stream>>>(xin_bf, attn, fidx, attn2_bf,
                                            addk_bf, kabar_bf);
  gemm_val_k<<<dim3(2, 8, 8), 256, 0, stream>>>(kabar_bf, Wcat_bf, Y);
  k_combine<<<1024, 256, 0, stream>>>(q, Wmix, Y, s1, s2, bval, out);
}

// Round 14
// 206.198 us; speedup vs baseline: 1.1218x; 1.1218x over previous
//
#include <hip/hip_runtime.h>

typedef unsigned short ushort_t;
typedef __attribute__((ext_vector_type(8))) short bh8;     // 8 bf16 (4 VGPRs)
typedef __attribute__((ext_vector_type(4))) float f4;      // 4 fp32 acc
typedef __attribute__((ext_vector_type(4))) unsigned int u4;

__device__ __forceinline__ ushort_t f2bf(float f) {
  unsigned u = __float_as_uint(f);
  return (ushort_t)((u + 0x7FFFu + ((u >> 16) & 1u)) >> 16);
}
__device__ __forceinline__ float bf2f(ushort_t v) {
  return __uint_as_float(((unsigned)v) << 16);
}

// ---------------------------------------------------------------------------
// bf16 MFMA GEMM core, abt form, LDS passed in (20480 B: As 10240 + Bs 10240)
// ---------------------------------------------------------------------------
template <typename OutT>
__device__ __forceinline__ void gemm_abt_core(
    char* smem,
    const ushort_t* __restrict__ A, const ushort_t* __restrict__ B,
    OutT* __restrict__ C, int ldA, int ldB, int ldC, int K, int m0, int n0)
{
  ushort_t* As = (ushort_t*)smem;
  ushort_t* Bs = (ushort_t*)(smem + 10240);
  int t = threadIdx.x;
  int lane = t & 63, w = t >> 6;
  int quad = lane >> 4, l15 = lane & 15;
  int wm = w >> 1, wn = w & 1;
  f4 acc[4][4];
  #pragma unroll
  for (int mi = 0; mi < 4; ++mi)
    #pragma unroll
    for (int ni = 0; ni < 4; ++ni) acc[mi][ni] = (f4)0.f;
  int row = t >> 1, kh = (t & 1) * 16;
  for (int k0 = 0; k0 < K; k0 += 32) {
    if (k0) __syncthreads();
    {
      const u4* ga = (const u4*)(A + (m0 + row) * ldA + k0 + kh);
      u4 v0 = ga[0], v1 = ga[1];
      u4* da = (u4*)(As + row * 40 + kh); da[0] = v0; da[1] = v1;
      const u4* gb = (const u4*)(B + (n0 + row) * ldB + k0 + kh);
      u4 u0 = gb[0], u1 = gb[1];
      u4* db = (u4*)(Bs + row * 40 + kh); db[0] = u0; db[1] = u1;
    }
    __syncthreads();
    bh8 af[4], bfv[4];
    #pragma unroll
    for (int mi = 0; mi < 4; ++mi)
      af[mi] = *(bh8*)(As + (wm * 64 + mi * 16 + l15) * 40 + quad * 8);
    #pragma unroll
    for (int ni = 0; ni < 4; ++ni)
      bfv[ni] = *(bh8*)(Bs + (wn * 64 + ni * 16 + l15) * 40 + quad * 8);
    #pragma unroll
    for (int mi = 0; mi < 4; ++mi)
      #pragma unroll
      for (int ni = 0; ni < 4; ++ni)
        acc[mi][ni] = __builtin_amdgcn_mfma_f32_16x16x32_bf16(af[mi], bfv[ni], acc[mi][ni], 0, 0, 0);
  }
  #pragma unroll
  for (int mi = 0; mi < 4; ++mi)
    #pragma unroll
    for (int ni = 0; ni < 4; ++ni)
      #pragma unroll
      for (int r = 0; r < 4; ++r) {
        int mg = m0 + wm * 64 + mi * 16 + quad * 4 + r;
        int ng = n0 + wn * 64 + ni * 16 + l15;
        if constexpr (sizeof(OutT) == 4) C[mg * ldC + ng] = acc[mi][ni][r];
        else C[mg * ldC + ng] = (OutT)f2bf(acc[mi][ni][r]);
      }
}

// ---------------------------------------------------------------------------
// FUSED A: bf16 cast (blocks 0..2047) + offset fp32 GEMM (blocks 2048..2111)
// (round-13 lesson: keep the offset projection as a TILED GEMM — the inline
//  per-thread version re-read Woff 512x = 786 MB L2 traffic, +25 us.)
// ---------------------------------------------------------------------------
__global__ __launch_bounds__(256) void k_fused_cast_off(
    const float* __restrict__ q, const float* __restrict__ xin,
    const float* __restrict__ addk, const float* __restrict__ Wval,
    const float* __restrict__ Wattn, ushort_t* __restrict__ arena,
    const float* __restrict__ Woff, float* __restrict__ off_buf)
{
  if (blockIdx.x < 2048) {
    const int total4 = 1850240;
    for (int i = blockIdx.x * 256 + threadIdx.x; i < total4; i += 2048 * 256) {
      const float* src; ushort_t* dst; int e;
      if (i < 65536)        { src = q    + i * 4;            dst = arena + i * 4; }
      else if (i < 916352)  { e = i - 65536;  src = xin  + e * 4; dst = arena + 262144  + e * 4; }
      else if (i < 932736)  { e = i - 916352; src = addk + e * 4; dst = arena + 3665408 + e * 4; }
      else if (i < 1194880) {                     // Wcat: [Wv1 row | Wv2 row]
        e = i - 932736; int el = e * 4;           // el in [0, 1048576)
        int h = el >> 17, r = el & 131071;
        int c = r >> 9, k = r & 511;
        src = Wval + (2 * h + (k >> 8)) * 65536 + c * 256 + (k & 255);
        dst = arena + 3730944 + el;
      }
      else if (i < 1325952) {                     // Wattn add-mats (h*4+4)
        e = i - 1194880; int el = e * 4;
        int h = el >> 16, off = el & 65535;
        src = Wattn + h * 262144 + 262144 + off;
        dst = arena + 5828096 + el;
      }
      else {                                      // Wattn level mats 0..31
        e = i - 1325952;
        src = Wattn + e * 4;
        dst = arena + 6352384 + e * 4;
      }
      float4 v = *(const float4*)src;
      ushort4 o; o.x = f2bf(v.x); o.y = f2bf(v.y); o.z = f2bf(v.z); o.w = f2bf(v.w);
      *(ushort4*)dst = o;
    }
  } else {
    // off = q @ Woff^T : M=1024 N=256 K=256, grid 4x16 flattened
    __shared__ float As[16][65];
    __shared__ float Bs[16][65];
    int e = blockIdx.x - 2048;
    int nx = e & 3, my = e >> 2;
    int m0 = my * 64, n0 = nx * 64;
    int t = threadIdx.x;
    int tm = t & 15, tn = t >> 4;
    int lr = t >> 4, lc = t & 15;
    float acc[4][4] = {};
    for (int k0 = 0; k0 < 256; k0 += 16) {
      #pragma unroll
      for (int i = 0; i < 4; ++i) {
        int r = lr + i * 16;
        As[lc][r] = q[(m0 + r) * 256 + k0 + lc];
        Bs[lc][r] = Woff[(n0 + r) * 256 + k0 + lc];
      }
      __syncthreads();
      #pragma unroll
      for (int k = 0; k < 16; ++k) {
        float a[4], b[4];
        #pragma unroll
        for (int i = 0; i < 4; ++i) a[i] = As[k][tm * 4 + i];
        #pragma unroll
        for (int j = 0; j < 4; ++j) b[j] = Bs[k][tn * 4 + j];
        #pragma unroll
        for (int i = 0; i < 4; ++i)
          #pragma unroll
          for (int j = 0; j < 4; ++j) acc[i][j] += a[i] * b[j];
      }
      __syncthreads();
    }
    #pragma unroll
    for (int i = 0; i < 4; ++i)
      #pragma unroll
      for (int j = 0; j < 4; ++j)
        off_buf[(m0 + tm * 4 + i) * 256 + n0 + tn * 4 + j] = acc[i][j];
  }
}

// ---------------------------------------------------------------------------
// FUSED B: gather indices (blocks 0..511, 2 queries/block) + gemm4 (512..543)
// ---------------------------------------------------------------------------
__global__ __launch_bounds__(256) void k_fused_idx_g4(
    const float* __restrict__ off_buf, const float* __restrict__ boff,
    const float* __restrict__ refpts, const int* __restrict__ shapes,
    const int* __restrict__ lvlst, int* __restrict__ fidx,
    const ushort_t* __restrict__ addk, const ushort_t* __restrict__ Wattn4,
    ushort_t* __restrict__ tmp)
{
  __shared__ __align__(16) char smem[20480];
  if (blockIdx.x < 512) {
    int t = threadIdx.x;
    int b = blockIdx.x * 2 + (t >> 7), tt = t & 127;   // tt = h*16 + l*4 + p
    int l = (tt >> 2) & 3;
    float off0 = off_buf[b * 256 + 2 * tt]     + boff[2 * tt];
    float off1 = off_buf[b * 256 + 2 * tt + 1] + boff[2 * tt + 1];
    int Hi = shapes[2 * l], Wi = shapes[2 * l + 1];
    float Hf = (float)Hi, Wf = (float)Wi;
    float r0 = refpts[b * 8 + 2 * l], r1 = refpts[b * 8 + 2 * l + 1];
    float l0 = fminf(fmaxf(r0 + off0 / Wf, 0.f), 0.999f);
    float l1 = fminf(fmaxf(r1 + off1 / Hf, 0.f), 0.999f);
    int i0 = (int)(l0 * Hf);
    int i1 = (int)(l1 * Wf);
    fidx[b * 128 + tt] = i0 + i1 * Hi + lvlst[l];
  } else {
    int e = blockIdx.x - 512;                  // 32 blocks: (2,2,8) flattened
    int h = e >> 2, rem = e & 3, my = rem >> 1, nx = rem & 1;
    gemm_abt_core<ushort_t>(smem, addk, Wattn4 + h * 65536, tmp + h * 65536,
                            256, 256, 256, 256, my * 128, nx * 128);
  }
}

// ---------------------------------------------------------------------------
// MFMA level-attention body (round-10 structure; flattened block index)
// ---------------------------------------------------------------------------
__device__ __forceinline__ void attn_mfma_body(
    char* smemc,
    const ushort_t* __restrict__ qbf, const ushort_t* __restrict__ xbf,
    const ushort_t* __restrict__ Wlvl, const int* __restrict__ fidx,
    float* __restrict__ attnP, int bx)
{
  unsigned* Bs = (unsigned*)smemc;               // 64*34 words = 8704 B
  ushort_t* As = (ushort_t*)(smemc + 8704);      // 64*72 ushort = 9216 B
  int* fis = (int*)(smemc + 17920);              // 1024 B
  float* Nlds = (float*)smemc;                   // 64*68 f32 (overlay)

  int h = bx >> 8, l = (bx >> 6) & 3, g = bx & 63;
  int ch = g & 3, g2 = g >> 2;
  int p = g2 >> 2, tg = g2 & 3;
  int c0 = ch * 64;
  int t = threadIdx.x;
  int lane = t & 63, w = t >> 6;
  int quad = lane >> 4, l15 = lane & 15;
  int qcol = p * 4 + tg;
  fis[t] = fidx[(tg * 256 + t) * 128 + h * 16 + l * 4 + p];
  __syncthreads();
  f4 acc[4];
  #pragma unroll
  for (int mi = 0; mi < 4; ++mi) acc[mi] = (f4)0.f;

  int cl = t & 63, sg = t >> 6;
  for (int jt = 0; jt < 4; ++jt) {
    if (jt) __syncthreads();
    unsigned vv[16];
    #pragma unroll
    for (int rr = 0; rr < 16; ++rr)
      vv[rr] = xbf[fis[jt * 64 + sg * 16 + rr] * 256 + c0 + cl];
    #pragma unroll
    for (int i = 0; i < 4; ++i) {
      uint2 w2; w2.x = vv[i * 4] | (vv[i * 4 + 1] << 16);
      w2.y = vv[i * 4 + 2] | (vv[i * 4 + 3] << 16);
      *(uint2*)&Bs[cl * 34 + sg * 8 + i * 2] = w2;
    }
    {
      int u = t >> 2, jj0 = (t & 3) * 16;
      const u4* src = (const u4*)(qbf + (u * 16 + qcol) * 256 + jt * 64 + jj0);
      u4 s0 = src[0], s1 = src[1];
      u4* dst = (u4*)(As + u * 72 + jj0);
      dst[0] = s0; dst[1] = s1;
    }
    __syncthreads();
    #pragma unroll
    for (int ks = 0; ks < 2; ++ks) {
      bh8 af[4], bfv;
      #pragma unroll
      for (int mi = 0; mi < 4; ++mi)
        af[mi] = *(bh8*)(As + (mi * 16 + l15) * 72 + ks * 32 + quad * 8);
      {
        const unsigned* bp = &Bs[(w * 16 + l15) * 34 + ks * 16 + quad * 4];
        uint2 b0 = *(const uint2*)bp;
        uint2 b1 = *(const uint2*)(bp + 2);
        u4 bb; bb.x = b0.x; bb.y = b0.y; bb.z = b1.x; bb.w = b1.y;
        bfv = __builtin_bit_cast(bh8, bb);
      }
      #pragma unroll
      for (int mi = 0; mi < 4; ++mi)
        acc[mi] = __builtin_amdgcn_mfma_f32_16x16x32_bf16(af[mi], bfv, acc[mi], 0, 0, 0);
    }
  }
  __syncthreads();
  #pragma unroll
  for (int mi = 0; mi < 4; ++mi)
    *(f4*)&Nlds[(w * 16 + l15) * 68 + mi * 16 + quad * 4] = acc[mi];
  __syncthreads();
  {
    int a = t >> 6, u = t & 63;
    const ushort_t* Wr = Wlvl + (h * 4 + l) * 65536 + (a * 64 + u) * 256 + c0;
    float s = 0.f;
    #pragma unroll
    for (int cc = 0; cc < 8; ++cc) {
      u4 wv = *(const u4*)(Wr + cc * 8);
      int cb = cc * 8;
      s += __uint_as_float(wv.x << 16)         * Nlds[(cb + 0) * 68 + u];
      s += __uint_as_float(wv.x & 0xffff0000u) * Nlds[(cb + 1) * 68 + u];
      s += __uint_as_float(wv.y << 16)         * Nlds[(cb + 2) * 68 + u];
      s += __uint_as_float(wv.y & 0xffff0000u) * Nlds[(cb + 3) * 68 + u];
      s += __uint_as_float(wv.z << 16)         * Nlds[(cb + 4) * 68 + u];
      s += __uint_as_float(wv.z & 0xffff0000u) * Nlds[(cb + 5) * 68 + u];
      s += __uint_as_float(wv.w << 16)         * Nlds[(cb + 6) * 68 + u];
      s += __uint_as_float(wv.w & 0xffff0000u) * Nlds[(cb + 7) * 68 + u];
    }
    attnP[ch * 131072 + (h * 16 + l * 4 + a) * 1024 + u * 16 + qcol] = s;
  }
}

// ---------------------------------------------------------------------------
// FUSED C: level attention (blocks 0..2047) + gemm5 (blocks 2048..2175)
// ---------------------------------------------------------------------------
__global__ __launch_bounds__(256) void k_fused_attn(
    const ushort_t* __restrict__ qbf, const ushort_t* __restrict__ xbf,
    const ushort_t* __restrict__ Wlvl, const int* __restrict__ fidx,
    float* __restrict__ attnP,
    const ushort_t* __restrict__ tmp, float* __restrict__ attn)
{
  __shared__ __align__(16) char smem[20480];
  int bx = blockIdx.x;
  if (bx < 2048) {
    attn_mfma_body(smem, qbf, xbf, Wlvl, fidx, attnP, bx);
  } else {
    int e = bx - 2048;                         // 128 blocks: (8,2,8) flattened
    int h = e >> 4, rem = e & 15, my = rem >> 3, nx = rem & 7;
    gemm_abt_core<float>(smem, tmp + h * 65536, qbf, attn + h * 278528 + 16384,
                         256, 256, 1024, 256, my * 128, nx * 128);
  }
}

// ---------------------------------------------------------------------------
// softmax: rows<16 = sum of the 4 attnP partial slices; rows>=16 from attn.
// ---------------------------------------------------------------------------
__global__ __launch_bounds__(256) void k_softmax(
    float* __restrict__ attn, const float* __restrict__ attnP,
    ushort_t* __restrict__ attn2bf, float* __restrict__ s1, float* __restrict__ s2)
{
  __shared__ float red[8][32];
  int h = blockIdx.y;
  int b = blockIdx.x * 32 + (threadIdx.x & 31);
  int rg = threadIdx.x >> 5;
  const int R0 = rg * 34;
  float* col = attn + h * 278528 + b;
  float v[34];
  float m = -1e30f;
  #pragma unroll
  for (int i = 0; i < 34; ++i) {
    int r = R0 + i;
    float x;
    if (r < 16) {
      int idx = (h * 16 + r) * 1024 + b;
      x = attnP[idx] + attnP[131072 + idx] + attnP[262144 + idx] + attnP[393216 + idx];
    } else {
      x = col[r * 1024];
    }
    v[i] = x;
    m = fmaxf(m, x);
  }
  red[rg][threadIdx.x & 31] = m;
  __syncthreads();
  #pragma unroll
  for (int j = 0; j < 8; ++j) m = fmaxf(m, red[j][threadIdx.x & 31]);
  float sum = 0.f;
  #pragma unroll
  for (int i = 0; i < 34; ++i) { v[i] = expf(v[i] - m); sum += v[i]; }
  __syncthreads();
  red[rg][threadIdx.x & 31] = sum;
  __syncthreads();
  float tot = 0.f;
  #pragma unroll
  for (int j = 0; j < 8; ++j) tot += red[j][threadIdx.x & 31];
  float inv = 1.f / tot;
  #pragma unroll
  for (int i = 0; i < 34; ++i) {
    int r = R0 + i;
    float x = v[i] * inv;
    if (r < 16) col[r * 1024] = x;
    else attn2bf[h * 262144 + (r - 16) * 1024 + b] = f2bf(x);
  }
  if (rg == 0) {
    float sa = 0.f;
    #pragma unroll
    for (int i = 0; i < 16; ++i) sa += v[i];
    float sn = sa * inv;
    s1[h * 1024 + b] = sn;
    s2[h * 1024 + b] = 1.f - sn;
  }
}

// ---------------------------------------------------------------------------
// FUSED D: kbar (blocks 0..1023) + TN GEMM abar (blocks 1024..1151)
// kbar writes kabar k=0..255; TN writes k=256..511.
// ---------------------------------------------------------------------------
__global__ __launch_bounds__(256) void k_fused_kbar_tn(
    const ushort_t* __restrict__ xbf, const float* __restrict__ attn,
    const int* __restrict__ fidx, const ushort_t* __restrict__ attn2,
    const ushort_t* __restrict__ addk, ushort_t* __restrict__ kabar)
{
  __shared__ __align__(16) unsigned Asu[128 * 20];
  __shared__ __align__(16) unsigned Bsu[128 * 20];
  if (blockIdx.x < 1024) {
    int h = blockIdx.x >> 7, b0 = (blockIdx.x & 127) * 8;
    int t = threadIdx.x;
    int qi = t >> 5, oct = t & 31;
    int b = b0 + qi;
    float sacc[8] = {};
    #pragma unroll
    for (int r = 0; r < 16; ++r) {
      float aw = attn[(h * 272 + r) * 1024 + b];
      int row = fidx[b * 128 + h * 16 + r];
      u4 v = *(const u4*)(xbf + row * 256 + oct * 8);
      sacc[0] += aw * __uint_as_float(v.x << 16);
      sacc[1] += aw * __uint_as_float(v.x & 0xffff0000u);
      sacc[2] += aw * __uint_as_float(v.y << 16);
      sacc[3] += aw * __uint_as_float(v.y & 0xffff0000u);
      sacc[4] += aw * __uint_as_float(v.z << 16);
      sacc[5] += aw * __uint_as_float(v.z & 0xffff0000u);
      sacc[6] += aw * __uint_as_float(v.w << 16);
      sacc[7] += aw * __uint_as_float(v.w & 0xffff0000u);
    }
    u4 o;
    o.x = (unsigned)f2bf(sacc[0]) | ((unsigned)f2bf(sacc[1]) << 16);
    o.y = (unsigned)f2bf(sacc[2]) | ((unsigned)f2bf(sacc[3]) << 16);
    o.z = (unsigned)f2bf(sacc[4]) | ((unsigned)f2bf(sacc[5]) << 16);
    o.w = (unsigned)f2bf(sacc[6]) | ((unsigned)f2bf(sacc[7]) << 16);
    *(u4*)(kabar + (h * 1024 + b) * 512 + oct * 8) = o;
  } else {
    int e = blockIdx.x - 1024;                 // 128 blocks: (2,8,8) flattened
    int h = e >> 4, rem = e & 15, my = rem >> 1, nx = rem & 1;
    const ushort_t* A = attn2 + h * 262144;
    const ushort_t* B = addk;
    ushort_t* C = kabar + h * 524288;
    int m0 = my * 128, n0 = nx * 128;
    int t = threadIdx.x;
    int lane = t & 63, w = t >> 6;
    int quad = lane >> 4, l15 = lane & 15;
    int wm = w >> 1, wn = w & 1;
    f4 acc[4][4];
    #pragma unroll
    for (int mi = 0; mi < 4; ++mi)
      #pragma unroll
      for (int ni = 0; ni < 4; ++ni) acc[mi][ni] = (f4)0.f;
    int col = t & 127, half = t >> 7;
    for (int k0 = 0; k0 < 256; k0 += 32) {
      if (k0) __syncthreads();
      #pragma unroll
      for (int i = 0; i < 4; ++i) {
        int kpp = half * 4 + i;
        int kk = k0 + kpp * 4;
        unsigned x0 = A[(kk + 0) * 1024 + m0 + col];
        unsigned x1 = A[(kk + 1) * 1024 + m0 + col];
        unsigned x2 = A[(kk + 2) * 1024 + m0 + col];
        unsigned x3 = A[(kk + 3) * 1024 + m0 + col];
        uint2 va; va.x = x0 | (x1 << 16); va.y = x2 | (x3 << 16);
        *(uint2*)&Asu[col * 20 + kpp * 2] = va;
        unsigned y0 = B[(kk + 0) * 256 + n0 + col];
        unsigned y1 = B[(kk + 1) * 256 + n0 + col];
        unsigned y2 = B[(kk + 2) * 256 + n0 + col];
        unsigned y3 = B[(kk + 3) * 256 + n0 + col];
        uint2 vb; vb.x = y0 | (y1 << 16); vb.y = y2 | (y3 << 16);
        *(uint2*)&Bsu[col * 20 + kpp * 2] = vb;
      }
      __syncthreads();
      bh8 af[4], bfv[4];
      #pragma unroll
      for (int mi = 0; mi < 4; ++mi)
        af[mi] = *(bh8*)((const ushort_t*)Asu + (wm * 64 + mi * 16 + l15) * 40 + quad * 8);
      #pragma unroll
      for (int ni = 0; ni < 4; ++ni)
        bfv[ni] = *(bh8*)((const ushort_t*)Bsu + (wn * 64 + ni * 16 + l15) * 40 + quad * 8);
      #pragma unroll
      for (int mi = 0; mi < 4; ++mi)
        #pragma unroll
        for (int ni = 0; ni < 4; ++ni)
          acc[mi][ni] = __builtin_amdgcn_mfma_f32_16x16x32_bf16(af[mi], bfv[ni], acc[mi][ni], 0, 0, 0);
    }
    #pragma unroll
    for (int mi = 0; mi < 4; ++mi)
      #pragma unroll
      for (int ni = 0; ni < 4; ++ni)
        #pragma unroll
        for (int r = 0; r < 4; ++r) {
          int mg = m0 + wm * 64 + mi * 16 + quad * 4 + r;
          int ng = n0 + wn * 64 + ni * 16 + l15;
          C[mg * 512 + 256 + ng] = f2bf(acc[mi][ni][r]);
        }
  }
}

// Y[h] = kabar[h] (1024x512) @ Wcat[h]^T (256 rows x 512 k, stride 131072/head)
__global__ __launch_bounds__(256) void gemm_val_k(
    const ushort_t* __restrict__ kabar, const ushort_t* __restrict__ Wcat,
    float* __restrict__ Y)
{
  __shared__ __align__(16) char smem[20480];
  int h = blockIdx.z;
  gemm_abt_core<float>(smem, kabar + h * 524288, Wcat + h * 131072, Y + h * 262144,
                       512, 512, 256, 512, blockIdx.y * 128, blockIdx.x * 128);
}

// ------------------------------- final combine ------------------------------
__global__ __launch_bounds__(256) void k_combine(
    const float* __restrict__ q, const float* __restrict__ Wmix,
    const float* __restrict__ Y,
    const float* __restrict__ s1, const float* __restrict__ s2,
    const float* __restrict__ bval, float* __restrict__ out)
{
  int b = blockIdx.x, c = threadIdx.x;
  float w[9];
  float m = -1e30f;
  #pragma unroll
  for (int j = 0; j < 9; ++j) { w[j] = Wmix[c * 9 + j]; m = fmaxf(m, w[j]); }
  float tot = 0.f;
  #pragma unroll
  for (int j = 0; j < 9; ++j) { w[j] = expf(w[j] - m); tot += w[j]; }
  float inv = 1.f / tot;
  float res = q[b * 256 + c] * w[8] * inv;
  #pragma unroll
  for (int hh = 0; hh < 8; ++hh) {
    float y = Y[(hh * 1024 + b) * 256 + c]
            + s1[hh * 1024 + b] * bval[(2 * hh) * 256 + c]
            + s2[hh * 1024 + b] * bval[(2 * hh + 1) * 256 + c];
    res += w[hh] * inv * y;
  }
  out[b * 256 + c] = res;
}

extern "C" void kernel_launch(void* const* d_in, const int* in_sizes, int n_in,
                              void* d_out, int out_size, void* d_ws, size_t ws_size,
                              hipStream_t stream) {
  (void)in_sizes; (void)n_in; (void)out_size; (void)ws_size;
  const float* q      = (const float*)d_in[0];
  const float* refpts = (const float*)d_in[1];
  const float* xin    = (const float*)d_in[2];
  const int*   shapes = (const int*)d_in[3];
  const float* addk   = (const float*)d_in[4];
  const int*   lvlst  = (const int*)d_in[5];
  const float* Woff   = (const float*)d_in[6];
  const float* boff   = (const float*)d_in[7];
  const float* Wattn  = (const float*)d_in[8];
  const float* Wval   = (const float*)d_in[9];
  const float* bval   = (const float*)d_in[10];
  const float* Wmix   = (const float*)d_in[11];
  float* out = (float*)d_out;
  float* ws  = (float*)d_ws;

  int*   fidx    = (int*)ws;                  // [0, 131072)
  float* off_buf = ws + 131072;               // 262144 f
  float* s1      = ws + 393216;               // 8192
  float* s2      = ws + 401408;               // 8192
  float* attn    = ws + 409600;               // 8*272*1024 fp32 (dead after fused_d)
  float* Y       = ws + 409600;               // overlays attn (written by gemm_val_k)
  ushort_t* arena = (ushort_t*)(ws + 2637824);
  ushort_t* q_bf     = arena;                 // 262144
  ushort_t* xin_bf   = arena + 262144;        // 3403264
  ushort_t* addk_bf  = arena + 3665408;       // 65536
  ushort_t* Wcat_bf  = arena + 3730944;       // 1048576 (stride 131072/head)
  ushort_t* Wattn4_bf= arena + 5828096;       // 524288
  ushort_t* Wlvl_bf  = arena + 6352384;       // 2097152
  ushort_t* tmp_bf   = arena + 8449536;       // 524288
  ushort_t* attn2_bf = arena + 8973824;       // 2097152
  ushort_t* kabar_bf = arena + 11070976;      // 4194304 (8*1024*512)
  float* attnP = (float*)(arena + 15265280);  // 4 * 131072 f (per-ch partials)

  k_fused_cast_off<<<2112, 256, 0, stream>>>(q, xin, addk, Wval, Wattn, arena,
                                             Woff, off_buf);
  k_fused_idx_g4<<<544, 256, 0, stream>>>(off_buf, boff, refpts, shapes, lvlst,
                                          fidx, addk_bf, Wattn4_bf, tmp_bf);
  k_fused_attn<<<2176, 256, 0, stream>>>(q_bf, xin_bf, Wlvl_bf, fidx, attnP,
                                         tmp_bf, attn);
  k_softmax<<<dim3(32, 8), 256, 0, stream>>>(attn, attnP, attn2_bf, s1, s2);
  k_fused_kbar_tn<<<1152, 256, 0, stream>>>(xin_bf, attn, fidx, attn2_bf,
                                            addk_bf, kabar_bf);
  gemm_val_k<<<dim3(2, 8, 8), 256, 0, stream>>>(kabar_bf, Wcat_bf, Y);
  k_combine<<<1024, 256, 0, stream>>>(q, Wmix, Y, s1, s2, bval, out);
}